// Round 1
// baseline (67.316 us; speedup 1.0000x reference)
//
#include <hip/hip_runtime.h>
#include <math.h>

#define NN 129
#define INC 129
#define OUTC 64
#define NE 4096

__device__ __forceinline__ float sigmf(float x) { return 1.0f / (1.0f + expf(-x)); }

// Kernel 1: pooling score + stable descending argsort (counting rank) + zero deg
__global__ void k_score_perm(const float* __restrict__ x, const float* __restrict__ p,
                             float* __restrict__ score, int* __restrict__ perm,
                             float* __restrict__ deg)
{
    __shared__ float sp[INC];
    __shared__ float snorm;
    __shared__ float ssc[NN];
    int t = threadIdx.x;
    if (t < INC) sp[t] = p[t];
    if (t < NN) deg[t] = 0.0f;
    __syncthreads();
    if (t == 0) {
        float s = 0.0f;
        for (int c = 0; c < INC; ++c) s += sp[c] * sp[c];
        snorm = sqrtf(s);
    }
    __syncthreads();
    if (t < NN) {
        float acc = 0.0f;
        const float* xr = x + t * INC;
        for (int c = 0; c < INC; ++c) acc += xr[c] * sp[c];
        float sc = tanhf(acc / snorm);
        ssc[t] = sc;
        score[t] = sc;
    }
    __syncthreads();
    if (t < NN) {
        float mysc = ssc[t];
        int rank = 0;
        for (int j = 0; j < NN; ++j) {
            float oj = ssc[j];
            if (oj > mysc || (oj == mysc && j < t)) ++rank;
        }
        perm[rank] = t;   // perm[r] = original index of r-th largest score
    }
}

// Kernel 2: degree accumulation over edges (self-loop +1 added later)
__global__ void k_deg(const int* __restrict__ col, const float* __restrict__ ew,
                      float* __restrict__ deg)
{
    int e = blockIdx.x * blockDim.x + threadIdx.x;
    if (e < NE) atomicAdd(&deg[col[e]], ew[e]);
}

// Kernel 3: GRU step -> evolved weight W [129,129]. One block per output row i.
__global__ void k_gru(const float* __restrict__ x, const float* __restrict__ score,
                      const int* __restrict__ perm, const float* __restrict__ W0,
                      const float* __restrict__ w_ih, const float* __restrict__ w_hh,
                      const float* __restrict__ b_ih, const float* __restrict__ b_hh,
                      float* __restrict__ W)
{
    int i = blockIdx.x;
    int t = threadIdx.x;
    __shared__ float xt[INC];   // x_tilde row i
    __shared__ float h0[INC];   // W0 row i (hidden state)
    __shared__ int spi;
    __shared__ float ssc;
    if (t == 0) { int pi = perm[i]; spi = pi; ssc = score[pi]; }
    __syncthreads();
    int pi = spi; float sc = ssc;
    if (t < INC) {
        xt[t] = x[pi * INC + t] * sc;
        h0[t] = W0[i * INC + t];
    }
    __syncthreads();
    if (t < INC) {
        int j = t;
        float ar = b_ih[j],        az = b_ih[INC + j],   an = b_ih[2 * INC + j];
        float hr = b_hh[j],        hz = b_hh[INC + j],   hn = b_hh[2 * INC + j];
        const float* wr = w_ih + (size_t)j * INC;
        const float* wz = w_ih + (size_t)(INC + j) * INC;
        const float* wn = w_ih + (size_t)(2 * INC + j) * INC;
        const float* vr = w_hh + (size_t)j * INC;
        const float* vz = w_hh + (size_t)(INC + j) * INC;
        const float* vn = w_hh + (size_t)(2 * INC + j) * INC;
        for (int c = 0; c < INC; ++c) {
            float xv = xt[c], hv = h0[c];
            ar += xv * wr[c]; az += xv * wz[c]; an += xv * wn[c];
            hr += hv * vr[c]; hz += hv * vz[c]; hn += hv * vn[c];
        }
        float r    = sigmf(ar + hr);
        float z    = sigmf(az + hz);
        float cand = tanhf(an + r * hn);
        W[i * INC + j] = (1.0f - z) * cand + z * h0[j];
    }
}

// Kernel 4: dis = rsqrt(deg + selfloop)
__global__ void k_dis(const float* __restrict__ deg, float* __restrict__ dis)
{
    int t = threadIdx.x;
    if (t < NN) {
        float d = deg[t] + 1.0f;   // self-loop weight 1.0
        dis[t] = (d > 0.0f) ? rsqrtf(fmaxf(d, 1e-12f)) : 0.0f;
    }
}

// Kernel 5: xw = x @ W, and gcn init = self-loop term + bias
__global__ void k_xw(const float* __restrict__ x, const float* __restrict__ W,
                     const float* __restrict__ dis, const float* __restrict__ bias,
                     float* __restrict__ xw, float* __restrict__ gcn)
{
    int i = blockIdx.x, t = threadIdx.x;
    __shared__ float xl[INC];
    if (t < INC) xl[t] = x[i * INC + t];
    __syncthreads();
    if (t < INC) {
        float acc = 0.0f;
        for (int c = 0; c < INC; ++c) acc += xl[c] * W[c * INC + t];
        xw[i * INC + t] = acc;
        float di = dis[i];
        gcn[i * INC + t] = di * di * acc + bias[t];
    }
}

// Kernel 6: per-edge scatter with gcn_norm
__global__ void k_edges(const int* __restrict__ row, const int* __restrict__ col,
                        const float* __restrict__ ew, const float* __restrict__ dis,
                        const float* __restrict__ xw, float* __restrict__ gcn)
{
    int e = blockIdx.x, t = threadIdx.x;
    __shared__ int sr, sc;
    __shared__ float sn;
    if (t == 0) {
        int r = row[e], c = col[e];
        sr = r; sc = c;
        sn = dis[r] * ew[e] * dis[c];
    }
    __syncthreads();
    if (t < INC) atomicAdd(&gcn[sc * INC + t], sn * xw[sr * INC + t]);
}

// Kernel 7: ELU + final linear -> out [129, 64]
__global__ void k_out(const float* __restrict__ gcn, const float* __restrict__ lw,
                      const float* __restrict__ lb, float* __restrict__ out)
{
    int i = blockIdx.x, t = threadIdx.x;   // blockDim = 64
    __shared__ float hl[INC];
    for (int j = t; j < INC; j += 64) {
        float v = gcn[i * INC + j];
        hl[j] = (v > 0.0f) ? v : expm1f(v);
    }
    __syncthreads();
    float acc = lb[t];
    const float* wr = lw + (size_t)t * INC;
    for (int c = 0; c < INC; ++c) acc += hl[c] * wr[c];
    out[i * OUTC + t] = acc;
}

extern "C" void kernel_launch(void* const* d_in, const int* in_sizes, int n_in,
                              void* d_out, int out_size, void* d_ws, size_t ws_size,
                              hipStream_t stream)
{
    const float* x   = (const float*)d_in[0];
    const int*   ei  = (const int*)d_in[1];
    const float* ew  = (const float*)d_in[2];
    const float* pp  = (const float*)d_in[3];
    const float* W0  = (const float*)d_in[4];
    const float* wih = (const float*)d_in[5];
    const float* whh = (const float*)d_in[6];
    const float* bih = (const float*)d_in[7];
    const float* bhh = (const float*)d_in[8];
    const float* cb  = (const float*)d_in[9];
    const float* lw  = (const float*)d_in[10];
    const float* lb  = (const float*)d_in[11];
    float* out = (float*)d_out;

    char* ws = (char*)d_ws;
    float* score = (float*)(ws + 0);           // 129 f32
    int*   perm  = (int*)  (ws + 640);         // 129 i32
    float* deg   = (float*)(ws + 1280);        // 129 f32
    float* dis   = (float*)(ws + 1920);        // 129 f32
    float* W     = (float*)(ws + 2560);        // 129*129 f32 (66564 B)
    float* xw    = (float*)(ws + 2560 + 69632);        // 129*129 f32
    float* gcn   = (float*)(ws + 2560 + 2 * 69632);    // 129*129 f32

    const int* row = ei;        // edge_index[0]
    const int* col = ei + NE;   // edge_index[1]

    k_score_perm<<<1, 192, 0, stream>>>(x, pp, score, perm, deg);
    k_deg<<<(NE + 255) / 256, 256, 0, stream>>>(col, ew, deg);
    k_gru<<<NN, 192, 0, stream>>>(x, score, perm, W0, wih, whh, bih, bhh, W);
    k_dis<<<1, 192, 0, stream>>>(deg, dis);
    k_xw<<<NN, 192, 0, stream>>>(x, W, dis, cb, xw, gcn);
    k_edges<<<NE, 192, 0, stream>>>(row, col, ew, dis, xw, gcn);
    k_out<<<NN, 64, 0, stream>>>(gcn, lw, lb, out);
}

// Round 2
// 42.287 us; speedup vs baseline: 1.5919x; 1.5919x over previous
//
#include <hip/hip_runtime.h>
#include <math.h>

#define NN 129
#define INC 129
#define OUTC 64
#define NE 4096

__device__ __forceinline__ float sigmf(float x) { return 1.0f / (1.0f + expf(-x)); }

// Kernel 1: block 0 -> pooling score + stable descending argsort (counting rank);
//           blocks 1..NN -> per-node degree gather + dis = rsqrt(deg+1)
__global__ void k_prep(const float* __restrict__ x, const float* __restrict__ p,
                       const int* __restrict__ col, const float* __restrict__ ew,
                       float* __restrict__ score, int* __restrict__ perm,
                       float* __restrict__ dis)
{
    int t = threadIdx.x;
    if (blockIdx.x == 0) {
        __shared__ float sp[INC];
        __shared__ float snorm;
        __shared__ float ssc[NN];
        if (t < INC) sp[t] = p[t];
        __syncthreads();
        if (t == 0) {
            float s = 0.0f;
            for (int c = 0; c < INC; ++c) s += sp[c] * sp[c];
            snorm = sqrtf(s);
        }
        __syncthreads();
        if (t < NN) {
            float acc = 0.0f;
            const float* xr = x + t * INC;
            for (int c = 0; c < INC; ++c) acc += xr[c] * sp[c];
            float sc = tanhf(acc / snorm);
            ssc[t] = sc;
            score[t] = sc;
        }
        __syncthreads();
        if (t < NN) {
            float mysc = ssc[t];
            int rank = 0;
            for (int j = 0; j < NN; ++j) {
                float oj = ssc[j];
                if (oj > mysc || (oj == mysc && j < t)) ++rank;
            }
            perm[rank] = t;   // perm[r] = original index of r-th largest score
        }
    } else {
        int node = blockIdx.x - 1;           // 0..NN-1
        float acc = 0.0f;
        for (int e = t; e < NE; e += blockDim.x) {
            float w = ew[e];
            if (col[e] == node) acc += w;
        }
        // wave reduce
        for (int off = 32; off > 0; off >>= 1) acc += __shfl_xor(acc, off, 64);
        __shared__ float wsum[4];
        int wv = t >> 6, ln = t & 63;
        if (ln == 0) wsum[wv] = acc;
        __syncthreads();
        if (t == 0) {
            float d = 1.0f;  // self-loop
            int nw = blockDim.x >> 6;
            for (int w = 0; w < nw; ++w) d += wsum[w];
            dis[node] = rsqrtf(fmaxf(d, 1e-12f));
        }
    }
}

// Kernel 2: GRU -> evolved W. One wave (64 lanes) per output element (i,j).
__global__ void k_gru(const float* __restrict__ x, const float* __restrict__ score,
                      const int* __restrict__ perm, const float* __restrict__ W0,
                      const float* __restrict__ w_ih, const float* __restrict__ w_hh,
                      const float* __restrict__ b_ih, const float* __restrict__ b_hh,
                      float* __restrict__ W)
{
    int wid = (blockIdx.x * blockDim.x + threadIdx.x) >> 6;
    int lane = threadIdx.x & 63;
    if (wid >= NN * INC) return;
    int i = wid / INC;
    int j = wid - i * INC;
    int pi = perm[i];
    float sc = score[pi];
    const float* xr = x  + (size_t)pi * INC;
    const float* h0 = W0 + (size_t)i * INC;
    const float* wr = w_ih + (size_t)j * INC;
    const float* wz = wr + (size_t)INC * INC;
    const float* wn = wz + (size_t)INC * INC;
    const float* vr = w_hh + (size_t)j * INC;
    const float* vz = vr + (size_t)INC * INC;
    const float* vn = vz + (size_t)INC * INC;

    float sr = 0.f, szv = 0.f, an = 0.f, hn = 0.f;
    for (int c = lane; c < INC; c += 64) {
        float xv = xr[c] * sc;
        float hv = h0[c];
        sr  += xv * wr[c] + hv * vr[c];
        szv += xv * wz[c] + hv * vz[c];
        an  += xv * wn[c];
        hn  += hv * vn[c];
    }
    for (int off = 32; off > 0; off >>= 1) {
        sr  += __shfl_xor(sr,  off, 64);
        szv += __shfl_xor(szv, off, 64);
        an  += __shfl_xor(an,  off, 64);
        hn  += __shfl_xor(hn,  off, 64);
    }
    if (lane == 0) {
        float r    = sigmf(sr  + b_ih[j]           + b_hh[j]);
        float z    = sigmf(szv + b_ih[INC + j]     + b_hh[INC + j]);
        float cand = tanhf(an + b_ih[2 * INC + j] + r * (hn + b_hh[2 * INC + j]));
        W[(size_t)i * INC + j] = (1.0f - z) * cand + z * h0[j];
    }
}

// Kernel 3: xw = x @ W, and gcn init = self-loop term + bias
__global__ void k_xw(const float* __restrict__ x, const float* __restrict__ W,
                     const float* __restrict__ dis, const float* __restrict__ bias,
                     float* __restrict__ xw, float* __restrict__ gcn)
{
    int i = blockIdx.x, t = threadIdx.x;
    __shared__ float xl[INC];
    if (t < INC) xl[t] = x[i * INC + t];
    __syncthreads();
    if (t < INC) {
        float acc = 0.0f;
        for (int c = 0; c < INC; ++c) acc += xl[c] * W[c * INC + t];
        xw[i * INC + t] = acc;
        float di = dis[i];
        gcn[i * INC + t] = di * di * acc + bias[t];
    }
}

// Kernel 4: per-edge scatter with gcn_norm, flattened over (edge, feature)
__global__ void k_edges(const int* __restrict__ row, const int* __restrict__ col,
                        const float* __restrict__ ew, const float* __restrict__ dis,
                        const float* __restrict__ xw, float* __restrict__ gcn)
{
    int idx = blockIdx.x * blockDim.x + threadIdx.x;
    if (idx < NE * INC) {
        int e = idx / INC;
        int f = idx - e * INC;
        int r = row[e], c = col[e];
        float nrm = dis[r] * ew[e] * dis[c];
        atomicAdd(&gcn[c * INC + f], nrm * xw[r * INC + f]);
    }
}

// Kernel 5: ELU + final linear -> out [129, 64]
__global__ void k_out(const float* __restrict__ gcn, const float* __restrict__ lw,
                      const float* __restrict__ lb, float* __restrict__ out)
{
    int i = blockIdx.x, t = threadIdx.x;   // blockDim = 64
    __shared__ float hl[INC];
    for (int j = t; j < INC; j += 64) {
        float v = gcn[i * INC + j];
        hl[j] = (v > 0.0f) ? v : expm1f(v);
    }
    __syncthreads();
    float acc = lb[t];
    const float* wr = lw + (size_t)t * INC;
    for (int c = 0; c < INC; ++c) acc += hl[c] * wr[c];
    out[i * OUTC + t] = acc;
}

extern "C" void kernel_launch(void* const* d_in, const int* in_sizes, int n_in,
                              void* d_out, int out_size, void* d_ws, size_t ws_size,
                              hipStream_t stream)
{
    const float* x   = (const float*)d_in[0];
    const int*   ei  = (const int*)d_in[1];
    const float* ew  = (const float*)d_in[2];
    const float* pp  = (const float*)d_in[3];
    const float* W0  = (const float*)d_in[4];
    const float* wih = (const float*)d_in[5];
    const float* whh = (const float*)d_in[6];
    const float* bih = (const float*)d_in[7];
    const float* bhh = (const float*)d_in[8];
    const float* cb  = (const float*)d_in[9];
    const float* lw  = (const float*)d_in[10];
    const float* lb  = (const float*)d_in[11];
    float* out = (float*)d_out;

    char* ws = (char*)d_ws;
    float* score = (float*)(ws + 0);           // 129 f32
    int*   perm  = (int*)  (ws + 640);         // 129 i32
    float* dis   = (float*)(ws + 1280);        // 129 f32
    float* W     = (float*)(ws + 2048);        // 129*129 f32
    float* xw    = (float*)(ws + 2048 + 69632);
    float* gcn   = (float*)(ws + 2048 + 2 * 69632);

    const int* row = ei;        // edge_index[0]
    const int* col = ei + NE;   // edge_index[1]

    k_prep<<<NN + 1, 192, 0, stream>>>(x, pp, col, ew, score, perm, dis);

    int gru_waves  = NN * INC;                       // 16641
    int gru_blocks = (gru_waves * 64 + 255) / 256;   // 4161
    k_gru<<<gru_blocks, 256, 0, stream>>>(x, score, perm, W0, wih, whh, bih, bhh, W);

    k_xw<<<NN, 192, 0, stream>>>(x, W, dis, cb, xw, gcn);

    int items = NE * INC;                            // 528384
    k_edges<<<(items + 255) / 256, 256, 0, stream>>>(row, col, ew, dis, xw, gcn);

    k_out<<<NN, 64, 0, stream>>>(gcn, lw, lb, out);
}